// Round 7
// baseline (3986.990 us; speedup 1.0000x reference)
//
#include <hip/hip_runtime.h>

// PlasticLSTM: T=256, B=32, I=128, H=256, 4H=1024, CLIP=2
// d_in: x[T,B,I], Wx[4H,I], bx[4H], Wh[4H,H], bh[4H], w_mod[1,H], b_mod[1],
//       w_fan[H,1], b_fan[H], alpha[H,H]   (all fp32)
// d_out: hs[T,B,H] ++ h[B,H] ++ c[B,H] ++ hebb[B,H,H]  (fp32, concat flat)
//
// Register-budget model (rounds 4-6): at 1024 thr (4 waves/SIMD) the unified
// arch+accum budget is 128/wave. hebb (32 half2) sits in the accum half;
// round 4 (~95 total) ran clean, round 5/6 (~158: +32 resident alpha, +32
// prefetch) spilled ~30 regs to scratch (WRITE_SIZE 17.2->32.6 MB).
// This round: rolling (not resident) alpha pipeline (8 regs) + rolling weight
// prefetch (32 regs, transient) => peak ~110 < 128.

#define TT 256
#define BB 32
#define II 128
#define HH 256
#define G4 1024

typedef _Float16 h2_t __attribute__((ext_vector_type(2)));

__device__ __forceinline__ float sigm(float x) {
    return 1.0f / (1.0f + __expf(-x));
}
__device__ __forceinline__ float tanhfast(float x) {
    return 1.0f - 2.0f / (__expf(2.0f * x) + 1.0f);
}
__device__ __forceinline__ unsigned pkh(float lo, float hi) {
    h2_t v;
    v.x = (_Float16)lo;
    v.y = (_Float16)hi;
    return __builtin_bit_cast(unsigned, v);
}

#if __has_builtin(__builtin_amdgcn_fdot2)
__device__ __forceinline__ float dot2(unsigned a, unsigned b, float c) {
    return __builtin_amdgcn_fdot2(__builtin_bit_cast(h2_t, a),
                                  __builtin_bit_cast(h2_t, b), c, false);
}
#else
__device__ __forceinline__ float dot2(unsigned a, unsigned b, float c) {
    h2_t av = __builtin_bit_cast(h2_t, a), bv = __builtin_bit_cast(h2_t, b);
    return c + (float)av.x * (float)bv.x + (float)av.y * (float)bv.y;
}
#endif

__device__ __forceinline__ h2_t pkfma(h2_t a, h2_t b, h2_t c) {
#if __has_builtin(__builtin_elementwise_fma)
    return __builtin_elementwise_fma(a, b, c);
#else
    return a * b + c;
#endif
}
__device__ __forceinline__ h2_t clip2h(h2_t x) {
    const h2_t lo = {(_Float16)-2.0f, (_Float16)-2.0f};
    const h2_t hi = {(_Float16)2.0f, (_Float16)2.0f};
#if __has_builtin(__builtin_elementwise_max) && __has_builtin(__builtin_elementwise_min)
    return __builtin_elementwise_min(__builtin_elementwise_max(x, lo), hi);
#else
    h2_t r = x;
    r.x = r.x < lo.x ? lo.x : (r.x > hi.x ? hi.x : r.x);
    r.y = r.y < lo.y ? lo.y : (r.y > hi.y ? hi.y : r.y);
    return r;
#endif
}

// ---------------------------------------------------------------------------
// Wd3 layout: idx = ro*4096 + g*4 + ri  (ro in [0,8), ri in [0,4), g in [0,1024))
//   entry = uint4 of 8 f16 = Wh[g][8*r8 .. 8*r8+7], r8 = 4*ro + ri.
// ---------------------------------------------------------------------------
__global__ __launch_bounds__(256) void prep_wd3(const float* __restrict__ Wh,
                                                uint4* __restrict__ Wd3) {
    int idx = blockIdx.x * 256 + threadIdx.x;   // 32768
    int ro = idx >> 12, rem = idx & 4095;
    int g = rem >> 2, ri = rem & 3;
    int r8 = 4 * ro + ri;
    const float4* s = (const float4*)(Wh + (size_t)g * HH + (r8 << 3));
    float4 a = s[0], b2 = s[1];
    uint4 o;
    o.x = pkh(a.x, a.y);
    o.y = pkh(a.z, a.w);
    o.z = pkh(b2.x, b2.y);
    o.w = pkh(b2.z, b2.w);
    Wd3[idx] = o;
}

// ---------------------------------------------------------------------------
// alQ layout: idx = p4*256 + k  ->  uint4; component j = f16 pair
//   { alpha[2*(4*p4+j)][k], alpha[2*(4*p4+j)+1][k] }.
// ---------------------------------------------------------------------------
__global__ __launch_bounds__(256) void prep_alq(const float* __restrict__ alpha,
                                                uint4* __restrict__ alQ) {
    int idx = blockIdx.x * 256 + threadIdx.x;   // 8192
    int p4 = idx >> 8, k = idx & 255;
    uint4 o;
    unsigned r[4];
#pragma unroll
    for (int j = 0; j < 4; ++j) {
        int p = 4 * p4 + j;
        float a0 = alpha[(size_t)(2 * p) * HH + k];
        float a1 = alpha[(size_t)(2 * p + 1) * HH + k];
        r[j] = pkh(a0, a1);
    }
    o.x = r[0]; o.y = r[1]; o.z = r[2]; o.w = r[3];
    alQ[idx] = o;
}

// ---------------------------------------------------------------------------
// xf[t,b,g] = sum_i x[t,b,i]*Wx[g,i] + bx[g] + bh[g]
// ---------------------------------------------------------------------------
__global__ __launch_bounds__(256) void xf_gemm(const float* __restrict__ x,
                                               const float* __restrict__ Wx,
                                               const float* __restrict__ bx,
                                               const float* __restrict__ bh,
                                               float* __restrict__ xf) {
    __shared__ float As[64][37];
    __shared__ float Bs[64][37];
    const int tid = threadIdx.x;
    const int tx = tid & 15, ty = tid >> 4;
    const int m0 = blockIdx.y << 6;
    const int n0 = blockIdx.x << 6;
    float c[4][4] = {};

    for (int k0 = 0; k0 < II; k0 += 32) {
#pragma unroll
        for (int hh = 0; hh < 2; ++hh) {
            int row = (tid >> 3) + (hh << 5);
            int col = (tid & 7) << 2;
            float4 va = *(const float4*)(x + (size_t)(m0 + row) * II + k0 + col);
            As[row][col] = va.x; As[row][col + 1] = va.y;
            As[row][col + 2] = va.z; As[row][col + 3] = va.w;
            float4 vb = *(const float4*)(Wx + (size_t)(n0 + row) * II + k0 + col);
            Bs[row][col] = vb.x; Bs[row][col + 1] = vb.y;
            Bs[row][col + 2] = vb.z; Bs[row][col + 3] = vb.w;
        }
        __syncthreads();
#pragma unroll
        for (int kk = 0; kk < 32; ++kk) {
            float a[4], bb[4];
#pragma unroll
            for (int u = 0; u < 4; ++u) a[u] = As[(ty << 2) + u][kk];
#pragma unroll
            for (int v = 0; v < 4; ++v) bb[v] = Bs[(tx << 2) + v][kk];
#pragma unroll
            for (int u = 0; u < 4; ++u)
#pragma unroll
                for (int v = 0; v < 4; ++v)
                    c[u][v] = fmaf(a[u], bb[v], c[u][v]);
        }
        __syncthreads();
    }
    const int n = n0 + (tx << 2);
    float4 bxv = *(const float4*)(bx + n);
    float4 bhv = *(const float4*)(bh + n);
    float4 badd = {bxv.x + bhv.x, bxv.y + bhv.y, bxv.z + bhv.z, bxv.w + bhv.w};
#pragma unroll
    for (int u = 0; u < 4; ++u) {
        int m = m0 + (ty << 2) + u;
        float4 o = {c[u][0] + badd.x, c[u][1] + badd.y,
                    c[u][2] + badd.z, c[u][3] + badd.w};
        *(float4*)(xf + (size_t)m * G4 + n) = o;
    }
}

// ---------------------------------------------------------------------------
// hebb: 32 NAMED half2 registers per thread (accum half of the unified file).
// alpha: rolling 2-buffer stream (8 regs). weights: rolling 2-buffer (32 regs,
// transient to phase 1b).
// ---------------------------------------------------------------------------
#define HBP_FOREACH(X) \
    X(0) X(1) X(2) X(3) X(4) X(5) X(6) X(7) \
    X(8) X(9) X(10) X(11) X(12) X(13) X(14) X(15) \
    X(16) X(17) X(18) X(19) X(20) X(21) X(22) X(23) \
    X(24) X(25) X(26) X(27) X(28) X(29) X(30) X(31)

#define HBP_DECL(i) h2_t hp##i = {(_Float16)0.0f, (_Float16)0.0f};
#define HBP_OUT(i) \
    hbout[(size_t)(r0 + 2 * i) * HH + k]     = (float)hp##i.x; \
    hbout[(size_t)(r0 + 2 * i + 1) * HH + k] = (float)hp##i.y;

#define HBP_STEP(i, au, hou, hnu) { \
    h2_t al2 = __builtin_bit_cast(h2_t, au); \
    h2_t ho2 = __builtin_bit_cast(h2_t, hou); \
    h2_t hn2 = __builtin_bit_cast(h2_t, hnu); \
    hp##i = clip2h(pkfma(mj2, ho2, hp##i)); \
    h2_t hna = hn2 * al2; \
    pp = dot2(__builtin_bit_cast(unsigned, hna), \
              __builtin_bit_cast(unsigned, hp##i), pp); }

// AV is a register (rolling alpha buffer)
#define HBP_CHUNK(q, AV, i0, i1, i2, i3) { \
    uint4 ho = hfO4[hq0 + (q)]; \
    uint4 hn = hfN4[hq0 + (q)]; \
    HBP_STEP(i0, AV.x, ho.x, hn.x) \
    HBP_STEP(i1, AV.y, ho.y, hn.y) \
    HBP_STEP(i2, AV.z, ho.z, hn.z) \
    HBP_STEP(i3, AV.w, ho.w, hn.w) }

// final deferred update only (no plast)
#define HBU_STEP(i, hou) { \
    h2_t ho2 = __builtin_bit_cast(h2_t, hou); \
    hp##i = clip2h(pkfma(mj2, ho2, hp##i)); }
#define HBU_CHUNK(q, i0, i1, i2, i3) { \
    uint4 ho = hfO4[hq0 + (q)]; \
    HBU_STEP(i0, ho.x) HBU_STEP(i1, ho.y) \
    HBU_STEP(i2, ho.z) HBU_STEP(i3, ho.w) }
#define HBU_ALL_CHUNKS \
    HBU_CHUNK(0, 0, 1, 2, 3)     HBU_CHUNK(1, 4, 5, 6, 7) \
    HBU_CHUNK(2, 8, 9, 10, 11)   HBU_CHUNK(3, 12, 13, 14, 15) \
    HBU_CHUNK(4, 16, 17, 18, 19) HBU_CHUNK(5, 20, 21, 22, 23) \
    HBU_CHUNK(6, 24, 25, 26, 27) HBU_CHUNK(7, 28, 29, 30, 31)

// prefetch weight chunk ro into 4 uint4 regs
#define PREF(B0, B1, B2, B3, ro) { \
    const uint4* _wp = wbase + ((size_t)(ro) << 12); \
    B0 = _wp[0]; B1 = _wp[1]; B2 = _wp[2]; B3 = _wp[3]; }

// consume weight chunk (16 dot2 against LDS h, uniform-address broadcasts)
#define PROC(W0, W1, W2, W3, ro) { \
    uint4 h0 = hfN4[4 * (ro)], h1 = hfN4[4 * (ro) + 1]; \
    uint4 h2 = hfN4[4 * (ro) + 2], h3 = hfN4[4 * (ro) + 3]; \
    ac0 = dot2(W0.x, h0.x, ac0); ac1 = dot2(W0.y, h0.y, ac1); \
    ac2 = dot2(W0.z, h0.z, ac2); ac3 = dot2(W0.w, h0.w, ac3); \
    ac0 = dot2(W1.x, h1.x, ac0); ac1 = dot2(W1.y, h1.y, ac1); \
    ac2 = dot2(W1.z, h1.z, ac2); ac3 = dot2(W1.w, h1.w, ac3); \
    ac0 = dot2(W2.x, h2.x, ac0); ac1 = dot2(W2.y, h2.y, ac1); \
    ac2 = dot2(W2.z, h2.z, ac2); ac3 = dot2(W2.w, h2.w, ac3); \
    ac0 = dot2(W3.x, h3.x, ac0); ac1 = dot2(W3.y, h3.y, ac1); \
    ac2 = dot2(W3.z, h3.z, ac2); ac3 = dot2(W3.w, h3.w, ac3); }

__global__ __launch_bounds__(1024, 1) void scan_kernel(
    const float* __restrict__ xf,      // [T,B,4H], biases folded
    const uint4* __restrict__ Wd3,     // f16 tiled Wh
    const uint4* __restrict__ alQ,     // f16 pair-packed alpha
    const float* __restrict__ w_mod,
    const float* __restrict__ b_mod,
    const float* __restrict__ w_fan,
    const float* __restrict__ b_fan,
    float* __restrict__ out) {
    const int b   = blockIdx.x;
    const int tid = threadIdx.x;
    const int k   = tid & (HH - 1);
    const int rg  = tid >> 8;        // 0..3
    const int r0  = rg << 6;
    const int hq0 = rg << 3;         // uint4 index of row r0 in hf_s

    __shared__ alignas(16) unsigned short hf_s[2][HH];
    __shared__ float fioj_s[G4];
    __shared__ float pp_s[4][HH];
    __shared__ float red_s[4];

    HBP_FOREACH(HBP_DECL)

    if (tid < HH) {
        hf_s[0][tid] = 0;
        hf_s[1][tid] = 0;
    }
    if (tid < 4) red_s[tid] = 0.0f;
    __syncthreads();

    const float bmod = b_mod[0];
    const float wf = w_fan[k], bf = b_fan[k], wm = w_mod[k];
    float creg = 0.0f, jreg = 0.0f, hnreg = 0.0f;

    const uint4* wbase = Wd3 + ((size_t)tid << 2);
    const uint4* aqp   = alQ + ((size_t)(rg << 3) << 8) + k;
    const float* xfp   = xf + (size_t)b * G4 + tid;

    for (int t = 0; t < TT; ++t) {
        float xfv = xfp[(size_t)t * BB * G4];   // in flight across phase 1a

        // issue at step top: weight chunk 0 + alpha chunks 0,1 (latency
        // covered by eta/mj + early hebb chunks)
        uint4 pb0, pb1, pb2, pb3, pc0, pc1, pc2, pc3;
        PREF(pb0, pb1, pb2, pb3, 0)
        uint4 aA = aqp[0 << 8];
        uint4 aB = aqp[1 << 8];

        // ---- Phase 1a: eta_{t-1}; deferred hebb update + plast(t) fused ---
        float eta = tanhfast(((red_s[0] + red_s[1]) + (red_s[2] + red_s[3])) + bmod);
        float mj = fmaf(eta, wf, bf) * jreg;    // 0 at t=0
        h2_t mj2;
        mj2.x = (_Float16)mj;
        mj2.y = mj2.x;
        const uint4* hfO4 = (const uint4*)hf_s[t & 1];        // h_{t-2}
        const uint4* hfN4 = (const uint4*)hf_s[(t & 1) ^ 1];  // h_{t-1}
        float pp = 0.0f;
        HBP_CHUNK(0, aA, 0, 1, 2, 3)      aA = aqp[2 << 8];
        HBP_CHUNK(1, aB, 4, 5, 6, 7)      aB = aqp[3 << 8];
        HBP_CHUNK(2, aA, 8, 9, 10, 11)    aA = aqp[4 << 8];
        HBP_CHUNK(3, aB, 12, 13, 14, 15)  aB = aqp[5 << 8];
        HBP_CHUNK(4, aA, 16, 17, 18, 19)  aA = aqp[6 << 8];
        HBP_CHUNK(5, aB, 20, 21, 22, 23)  aB = aqp[7 << 8];
        HBP_CHUNK(6, aA, 24, 25, 26, 27)
        HBP_CHUNK(7, aB, 28, 29, 30, 31)
        pp_s[rg][k] = pp;

        // ---- Phase 1b: gate matvec, rolling 2-buffer weight prefetch ------
        float ac0 = 0.f, ac1 = 0.f, ac2 = 0.f, ac3 = 0.f;
        PREF(pc0, pc1, pc2, pc3, 1)
        PROC(pb0, pb1, pb2, pb3, 0)
        PREF(pb0, pb1, pb2, pb3, 2)
        PROC(pc0, pc1, pc2, pc3, 1)
        PREF(pc0, pc1, pc2, pc3, 3)
        PROC(pb0, pb1, pb2, pb3, 2)
        PREF(pb0, pb1, pb2, pb3, 4)
        PROC(pc0, pc1, pc2, pc3, 3)
        PREF(pc0, pc1, pc2, pc3, 5)
        PROC(pb0, pb1, pb2, pb3, 4)
        PREF(pb0, pb1, pb2, pb3, 6)
        PROC(pc0, pc1, pc2, pc3, 5)
        PREF(pc0, pc1, pc2, pc3, 7)
        PROC(pb0, pb1, pb2, pb3, 6)
        PROC(pc0, pc1, pc2, pc3, 7)
        fioj_s[tid] = ((ac0 + ac1) + (ac2 + ac3)) + xfv;
        __syncthreads();

        // ---- Phase 2: cell update, redundant across the 4 row-groups ------
        float fg = sigm(fioj_s[k]);
        float ig = sigm(fioj_s[HH + k]);
        float og = sigm(fioj_s[2 * HH + k]);
        float jp = fioj_s[3 * HH + k]
                 + ((pp_s[0][k] + pp_s[1][k]) + (pp_s[2][k] + pp_s[3][k]));
        jreg = tanhfast(jp);
        creg = fmaf(fg, creg, ig * jreg);
        hnreg = og * tanhfast(creg);
        if (rg == 0) {   // waves 0-3, wave-uniform
            _Float16 hh = (_Float16)hnreg;
            hf_s[t & 1][k] = __builtin_bit_cast(unsigned short, hh);
            out[((size_t)t * BB + b) * HH + k] = hnreg;
            float e = creg * wm;
#pragma unroll
            for (int m = 32; m >= 1; m >>= 1) e += __shfl_xor(e, m, 64);
            if ((k & 63) == 0) red_s[k >> 6] = e;
        }
        __syncthreads();
    }

    // ---- Final deferred hebb update (step 255's delta) -------------------
    {
        float eta = tanhfast(((red_s[0] + red_s[1]) + (red_s[2] + red_s[3])) + bmod);
        float mj = fmaf(eta, wf, bf) * jreg;
        h2_t mj2;
        mj2.x = (_Float16)mj;
        mj2.y = mj2.x;
        const uint4* hfO4 = (const uint4*)hf_s[0];   // h_254 (TT even)
        HBU_ALL_CHUNKS
    }

    const size_t HS = (size_t)TT * BB * HH;
    if (rg == 0) {
        out[HS + (size_t)b * HH + k]           = hnreg;  // h_255
        out[HS + BB * HH + (size_t)b * HH + k] = creg;   // c_255
    }
    float* hbout = out + HS + 2 * BB * HH + (size_t)b * HH * HH;
    HBP_FOREACH(HBP_OUT)
}

// ---------------------------------------------------------------------------
extern "C" void kernel_launch(void* const* d_in, const int* in_sizes, int n_in,
                              void* d_out, int out_size, void* d_ws,
                              size_t ws_size, hipStream_t stream) {
    const float* x     = (const float*)d_in[0];
    const float* Wx    = (const float*)d_in[1];
    const float* bx    = (const float*)d_in[2];
    const float* Wh    = (const float*)d_in[3];
    const float* bh    = (const float*)d_in[4];
    const float* w_mod = (const float*)d_in[5];
    const float* b_mod = (const float*)d_in[6];
    const float* w_fan = (const float*)d_in[7];
    const float* b_fan = (const float*)d_in[8];
    const float* alpha = (const float*)d_in[9];
    float* out = (float*)d_out;

    float* xf  = (float*)d_ws;                                   // 32 MiB
    uint4* Wd3 = (uint4*)((char*)d_ws + 33554432);                // 512 KiB
    uint4* alQ = (uint4*)((char*)d_ws + 33554432 + 524288);       // 128 KiB

    hipLaunchKernelGGL(prep_wd3, dim3(128), dim3(256), 0, stream, Wh, Wd3);
    hipLaunchKernelGGL(prep_alq, dim3(32), dim3(256), 0, stream, alpha, alQ);
    hipLaunchKernelGGL(xf_gemm, dim3(16, 128), dim3(256), 0, stream,
                       x, Wx, bx, bh, xf);
    hipLaunchKernelGGL(scan_kernel, dim3(BB), dim3(1024), 0, stream,
                       xf, Wd3, alQ, w_mod, b_mod, w_fan, b_fan, out);
}

// Round 8
// 1459.214 us; speedup vs baseline: 2.7323x; 2.7323x over previous
//
#include <hip/hip_runtime.h>

// PlasticLSTM: T=256, B=32, I=128, H=256, 4H=1024, CLIP=2
// d_out: hs[T,B,H] ++ h[B,H] ++ c[B,H] ++ hebb[B,H,H]  (fp32, concat flat)
//
// Round-8 decomposition: 64 blocks = 2 per batch (split-K over the 256 rows).
//   role r = blockIdx>>5 owns rows r*128..r*128+127 of Wh-dot, hebb, alpha.
//   Per step each block publishes gate partials (1024 f32) + plast partials
//   (256 f32) via agent-scope bypass atomics + monotonic flag; partner spins
//   (relaxed), then phase 2 is computed redundantly in both blocks.
//   Pairing j <-> j+32 keeps both on one XCD (perf heuristic only;
//   correctness comes from agent-scope atomics).
// Register relief: hebb halves to 16 half2/thread -> no spill pressure
// (rounds 5-7 showed the 128-total arch+accum wall).

#define TT 256
#define BB 32
#define II 128
#define HH 256
#define G4 1024

typedef _Float16 h2_t __attribute__((ext_vector_type(2)));

__device__ __forceinline__ float sigm(float x) {
    return 1.0f / (1.0f + __expf(-x));
}
__device__ __forceinline__ float tanhfast(float x) {
    return 1.0f - 2.0f / (__expf(2.0f * x) + 1.0f);
}
__device__ __forceinline__ unsigned pkh(float lo, float hi) {
    h2_t v;
    v.x = (_Float16)lo;
    v.y = (_Float16)hi;
    return __builtin_bit_cast(unsigned, v);
}

#if __has_builtin(__builtin_amdgcn_fdot2)
__device__ __forceinline__ float dot2(unsigned a, unsigned b, float c) {
    return __builtin_amdgcn_fdot2(__builtin_bit_cast(h2_t, a),
                                  __builtin_bit_cast(h2_t, b), c, false);
}
#else
__device__ __forceinline__ float dot2(unsigned a, unsigned b, float c) {
    h2_t av = __builtin_bit_cast(h2_t, a), bv = __builtin_bit_cast(h2_t, b);
    return c + (float)av.x * (float)bv.x + (float)av.y * (float)bv.y;
}
#endif

__device__ __forceinline__ h2_t pkfma(h2_t a, h2_t b, h2_t c) {
#if __has_builtin(__builtin_elementwise_fma)
    return __builtin_elementwise_fma(a, b, c);
#else
    return a * b + c;
#endif
}
__device__ __forceinline__ h2_t clip2h(h2_t x) {
    const h2_t lo = {(_Float16)-2.0f, (_Float16)-2.0f};
    const h2_t hi = {(_Float16)2.0f, (_Float16)2.0f};
#if __has_builtin(__builtin_elementwise_max) && __has_builtin(__builtin_elementwise_min)
    return __builtin_elementwise_min(__builtin_elementwise_max(x, lo), hi);
#else
    h2_t r = x;
    r.x = r.x < lo.x ? lo.x : (r.x > hi.x ? hi.x : r.x);
    r.y = r.y < lo.y ? lo.y : (r.y > hi.y ? hi.y : r.y);
    return r;
#endif
}

// ---------------------------------------------------------------------------
// Wd3: idx = ro*4096 + g*4 + ri ; entry = 8 f16 of Wh[g][8*(4ro+ri) .. +7]
// ---------------------------------------------------------------------------
__global__ __launch_bounds__(256) void prep_wd3(const float* __restrict__ Wh,
                                                uint4* __restrict__ Wd3) {
    int idx = blockIdx.x * 256 + threadIdx.x;   // 32768
    int ro = idx >> 12, rem = idx & 4095;
    int g = rem >> 2, ri = rem & 3;
    int r8 = 4 * ro + ri;
    const float4* s = (const float4*)(Wh + (size_t)g * HH + (r8 << 3));
    float4 a = s[0], b2 = s[1];
    uint4 o;
    o.x = pkh(a.x, a.y);
    o.y = pkh(a.z, a.w);
    o.z = pkh(b2.x, b2.y);
    o.w = pkh(b2.z, b2.w);
    Wd3[idx] = o;
}

// ---------------------------------------------------------------------------
// alQ: idx = p4*256 + k -> uint4; comp j = f16 pair {alpha[2*(4p4+j)][k], +1}
// ---------------------------------------------------------------------------
__global__ __launch_bounds__(256) void prep_alq(const float* __restrict__ alpha,
                                                uint4* __restrict__ alQ) {
    int idx = blockIdx.x * 256 + threadIdx.x;   // 8192
    int p4 = idx >> 8, k = idx & 255;
    unsigned r[4];
#pragma unroll
    for (int j = 0; j < 4; ++j) {
        int p = 4 * p4 + j;
        float a0 = alpha[(size_t)(2 * p) * HH + k];
        float a1 = alpha[(size_t)(2 * p + 1) * HH + k];
        r[j] = pkh(a0, a1);
    }
    uint4 o; o.x = r[0]; o.y = r[1]; o.z = r[2]; o.w = r[3];
    alQ[idx] = o;
}

// flags must start <1 every launch (don't trust poison alone)
__global__ void clear_flags(int* __restrict__ f) {
    f[blockIdx.x * 256 + threadIdx.x] = 0;
}

// ---------------------------------------------------------------------------
// xf[t,b,g] = sum_i x[t,b,i]*Wx[g,i] + bx[g] + bh[g]
// ---------------------------------------------------------------------------
__global__ __launch_bounds__(256) void xf_gemm(const float* __restrict__ x,
                                               const float* __restrict__ Wx,
                                               const float* __restrict__ bx,
                                               const float* __restrict__ bh,
                                               float* __restrict__ xf) {
    __shared__ float As[64][37];
    __shared__ float Bs[64][37];
    const int tid = threadIdx.x;
    const int tx = tid & 15, ty = tid >> 4;
    const int m0 = blockIdx.y << 6;
    const int n0 = blockIdx.x << 6;
    float c[4][4] = {};

    for (int k0 = 0; k0 < II; k0 += 32) {
#pragma unroll
        for (int hh = 0; hh < 2; ++hh) {
            int row = (tid >> 3) + (hh << 5);
            int col = (tid & 7) << 2;
            float4 va = *(const float4*)(x + (size_t)(m0 + row) * II + k0 + col);
            As[row][col] = va.x; As[row][col + 1] = va.y;
            As[row][col + 2] = va.z; As[row][col + 3] = va.w;
            float4 vb = *(const float4*)(Wx + (size_t)(n0 + row) * II + k0 + col);
            Bs[row][col] = vb.x; Bs[row][col + 1] = vb.y;
            Bs[row][col + 2] = vb.z; Bs[row][col + 3] = vb.w;
        }
        __syncthreads();
#pragma unroll
        for (int kk = 0; kk < 32; ++kk) {
            float a[4], bb[4];
#pragma unroll
            for (int u = 0; u < 4; ++u) a[u] = As[(ty << 2) + u][kk];
#pragma unroll
            for (int v = 0; v < 4; ++v) bb[v] = Bs[(tx << 2) + v][kk];
#pragma unroll
            for (int u = 0; u < 4; ++u)
#pragma unroll
                for (int v = 0; v < 4; ++v)
                    c[u][v] = fmaf(a[u], bb[v], c[u][v]);
        }
        __syncthreads();
    }
    const int n = n0 + (tx << 2);
    float4 bxv = *(const float4*)(bx + n);
    float4 bhv = *(const float4*)(bh + n);
    float4 badd = {bxv.x + bhv.x, bxv.y + bhv.y, bxv.z + bhv.z, bxv.w + bhv.w};
#pragma unroll
    for (int u = 0; u < 4; ++u) {
        int m = m0 + (ty << 2) + u;
        float4 o = {c[u][0] + badd.x, c[u][1] + badd.y,
                    c[u][2] + badd.z, c[u][3] + badd.w};
        *(float4*)(xf + (size_t)m * G4 + n) = o;
    }
}

// ---------------------------------------------------------------------------
// hebb: 16 NAMED half2 registers per thread (rows r*128+rg*32+2i, 2i+1).
// ---------------------------------------------------------------------------
#define HBQ_FOREACH(X) \
    X(0) X(1) X(2) X(3) X(4) X(5) X(6) X(7) \
    X(8) X(9) X(10) X(11) X(12) X(13) X(14) X(15)

#define HBQ_DECL(i) h2_t hp##i = {(_Float16)0.0f, (_Float16)0.0f};
#define HBQ_OUT(i) \
    hbout[(size_t)(r0g + 2 * i) * HH + k]     = (float)hp##i.x; \
    hbout[(size_t)(r0g + 2 * i + 1) * HH + k] = (float)hp##i.y;

#define HBQ_STEP(i, au, hou, hnu) { \
    h2_t al2 = __builtin_bit_cast(h2_t, au); \
    h2_t ho2 = __builtin_bit_cast(h2_t, hou); \
    h2_t hn2 = __builtin_bit_cast(h2_t, hnu); \
    hp##i = clip2h(pkfma(mj2, ho2, hp##i)); \
    h2_t hna = hn2 * al2; \
    pp = dot2(__builtin_bit_cast(unsigned, hna), \
              __builtin_bit_cast(unsigned, hp##i), pp); }

#define HBQ_CHUNK(q, i0, i1, i2, i3) { \
    uint4 av = aqp[(q) << 8]; \
    uint4 ho = hfO4[hb + (q)]; \
    uint4 hn = hfN4[hb + (q)]; \
    HBQ_STEP(i0, av.x, ho.x, hn.x) \
    HBQ_STEP(i1, av.y, ho.y, hn.y) \
    HBQ_STEP(i2, av.z, ho.z, hn.z) \
    HBQ_STEP(i3, av.w, ho.w, hn.w) }

#define HBQ_ALL \
    HBQ_CHUNK(0, 0, 1, 2, 3)   HBQ_CHUNK(1, 4, 5, 6, 7) \
    HBQ_CHUNK(2, 8, 9, 10, 11) HBQ_CHUNK(3, 12, 13, 14, 15)

#define HBV_STEP(i, hou) { \
    h2_t ho2 = __builtin_bit_cast(h2_t, hou); \
    hp##i = clip2h(pkfma(mj2, ho2, hp##i)); }
#define HBV_CHUNK(q, i0, i1, i2, i3) { \
    uint4 ho = hfO4[hb + (q)]; \
    HBV_STEP(i0, ho.x) HBV_STEP(i1, ho.y) \
    HBV_STEP(i2, ho.z) HBV_STEP(i3, ho.w) }
#define HBV_ALL \
    HBV_CHUNK(0, 0, 1, 2, 3)   HBV_CHUNK(1, 4, 5, 6, 7) \
    HBV_CHUNK(2, 8, 9, 10, 11) HBV_CHUNK(3, 12, 13, 14, 15)

__global__ __launch_bounds__(1024, 1) void scan_kernel(
    const float* __restrict__ xf,      // [T,B,4H], biases folded
    const uint4* __restrict__ Wd3,
    const uint4* __restrict__ alQ,
    const float* __restrict__ w_mod,
    const float* __restrict__ b_mod,
    const float* __restrict__ w_fan,
    const float* __restrict__ b_fan,
    float* __restrict__ exData,        // [32][2][2][1280] f32
    int* __restrict__ exFlag,          // [32][2] stride 32 ints
    float* __restrict__ out) {
    const int bid = blockIdx.x;
    const int r   = bid >> 5;          // role: rows r*128..r*128+127
    const int b   = bid & 31;          // batch element
    const int tid = threadIdx.x;
    const int k   = tid & (HH - 1);
    const int rg  = tid >> 8;          // 0..3
    const int hb  = r * 16 + rg * 4;   // uint4 base for this thread's rows
    const int r0g = r * 128 + rg * 32; // first hebb row owned

    __shared__ alignas(16) unsigned short hf_s[2][HH];
    __shared__ float fioj_s[G4];
    __shared__ float pp_s[4][HH];
    __shared__ float pps_s[HH];
    __shared__ float red_s[4];

    HBQ_FOREACH(HBQ_DECL)

    if (tid < HH) {
        hf_s[0][tid] = 0;
        hf_s[1][tid] = 0;
    }
    if (tid < 4) red_s[tid] = 0.0f;
    __syncthreads();

    const float bmod = b_mod[0];
    const float wf = w_fan[k], bf = b_fan[k], wm = w_mod[k];
    float creg = 0.0f, jreg = 0.0f, hnreg = 0.0f;

    const uint4* wbase = Wd3 + ((size_t)(r * 4) << 12) + (tid << 2);
    const uint4* aqp   = alQ + ((size_t)(r * 16 + rg * 4) << 8) + k;
    const float* xfp   = xf + (size_t)b * G4 + tid;

    float*       myEx  = exData + (size_t)((b * 2 + r) * 2) * 1280;
    const float* pEx   = exData + (size_t)((b * 2 + (1 - r)) * 2) * 1280;
    int*         myFlag = exFlag + (b * 2 + r) * 32;
    const int*   pFlag  = exFlag + (b * 2 + (1 - r)) * 32;

    for (int t = 0; t < TT; ++t) {
        float xfv = 0.0f;
        if (r == 0) xfv = xfp[(size_t)t * BB * G4];   // block-uniform

        // ---- Phase 1a: eta_{t-1}; deferred hebb update + plast(t) fused ---
        float eta = tanhfast(((red_s[0] + red_s[1]) + (red_s[2] + red_s[3])) + bmod);
        float mj = fmaf(eta, wf, bf) * jreg;    // 0 at t=0
        h2_t mj2;
        mj2.x = (_Float16)mj;
        mj2.y = mj2.x;
        const uint4* hfO4 = (const uint4*)hf_s[t & 1];        // h_{t-2}
        const uint4* hfN4 = (const uint4*)hf_s[(t & 1) ^ 1];  // h_{t-1}
        float pp = 0.0f;
        HBQ_ALL
        pp_s[rg][k] = pp;

        // ---- Phase 1b: half-K gate matvec (rows r*128 .. +127) ------------
        float ac0 = 0.f, ac1 = 0.f, ac2 = 0.f, ac3 = 0.f;
#pragma unroll
        for (int c = 0; c < 4; ++c) {
            const uint4* wp = wbase + ((size_t)c << 12);
            uint4 w0 = wp[0], w1 = wp[1], w2 = wp[2], w3 = wp[3];
            int hx = r * 16 + 4 * c;
            uint4 h0 = hfN4[hx], h1 = hfN4[hx + 1];
            uint4 h2 = hfN4[hx + 2], h3 = hfN4[hx + 3];
            ac0 = dot2(w0.x, h0.x, ac0); ac1 = dot2(w0.y, h0.y, ac1);
            ac2 = dot2(w0.z, h0.z, ac2); ac3 = dot2(w0.w, h0.w, ac3);
            ac0 = dot2(w1.x, h1.x, ac0); ac1 = dot2(w1.y, h1.y, ac1);
            ac2 = dot2(w1.z, h1.z, ac2); ac3 = dot2(w1.w, h1.w, ac3);
            ac0 = dot2(w2.x, h2.x, ac0); ac1 = dot2(w2.y, h2.y, ac1);
            ac2 = dot2(w2.z, h2.z, ac2); ac3 = dot2(w2.w, h2.w, ac3);
            ac0 = dot2(w3.x, h3.x, ac0); ac1 = dot2(w3.y, h3.y, ac1);
            ac2 = dot2(w3.z, h3.z, ac2); ac3 = dot2(w3.w, h3.w, ac3);
        }
        float part = ((ac0 + ac1) + (ac2 + ac3)) + xfv;
        fioj_s[tid] = part;
        float* myExT = myEx + (t & 1) * 1280;
        __hip_atomic_store(&myExT[tid], part, __ATOMIC_RELAXED,
                           __HIP_MEMORY_SCOPE_AGENT);
        __syncthreads();                                   // B1

        if (tid < HH) {
            float s = (pp_s[0][tid] + pp_s[1][tid])
                    + (pp_s[2][tid] + pp_s[3][tid]);
            pps_s[tid] = s;
            __hip_atomic_store(&myExT[G4 + tid], s, __ATOMIC_RELAXED,
                               __HIP_MEMORY_SCOPE_AGENT);
        }
        __syncthreads();                                   // B2 (drains stores)

        if (tid == 0) {
            __hip_atomic_store(myFlag, t + 1, __ATOMIC_RELEASE,
                               __HIP_MEMORY_SCOPE_AGENT);
            while (__hip_atomic_load(pFlag, __ATOMIC_RELAXED,
                                     __HIP_MEMORY_SCOPE_AGENT) < t + 1) {}
        }
        __syncthreads();                                   // B3

        // ---- Phase 2: combine partials, cell update (redundant) -----------
        const float* pExT = pEx + (t & 1) * 1280;
        float pf = __hip_atomic_load(&pExT[k], __ATOMIC_RELAXED,
                                     __HIP_MEMORY_SCOPE_AGENT);
        float pi = __hip_atomic_load(&pExT[HH + k], __ATOMIC_RELAXED,
                                     __HIP_MEMORY_SCOPE_AGENT);
        float po = __hip_atomic_load(&pExT[2 * HH + k], __ATOMIC_RELAXED,
                                     __HIP_MEMORY_SCOPE_AGENT);
        float pj = __hip_atomic_load(&pExT[3 * HH + k], __ATOMIC_RELAXED,
                                     __HIP_MEMORY_SCOPE_AGENT);
        float pq = __hip_atomic_load(&pExT[G4 + k], __ATOMIC_RELAXED,
                                     __HIP_MEMORY_SCOPE_AGENT);
        float fg = sigm(fioj_s[k] + pf);
        float ig = sigm(fioj_s[HH + k] + pi);
        float og = sigm(fioj_s[2 * HH + k] + po);
        float jp = (fioj_s[3 * HH + k] + pj) + (pps_s[k] + pq);
        jreg = tanhfast(jp);
        creg = fmaf(fg, creg, ig * jreg);
        hnreg = og * tanhfast(creg);
        if (rg == 0) {   // waves 0-3, wave-uniform
            _Float16 hh = (_Float16)hnreg;
            hf_s[t & 1][k] = __builtin_bit_cast(unsigned short, hh);
            if (r == 0) out[((size_t)t * BB + b) * HH + k] = hnreg;
            float e = creg * wm;
#pragma unroll
            for (int m = 32; m >= 1; m >>= 1) e += __shfl_xor(e, m, 64);
            if ((k & 63) == 0) red_s[k >> 6] = e;
        }
        __syncthreads();                                   // B4
    }

    // ---- Final deferred hebb update (step 255's delta) -------------------
    {
        float eta = tanhfast(((red_s[0] + red_s[1]) + (red_s[2] + red_s[3])) + bmod);
        float mj = fmaf(eta, wf, bf) * jreg;
        h2_t mj2;
        mj2.x = (_Float16)mj;
        mj2.y = mj2.x;
        const uint4* hfO4 = (const uint4*)hf_s[0];   // h_254 (TT even)
        HBV_ALL
    }

    const size_t HS = (size_t)TT * BB * HH;
    if (r == 0 && rg == 0) {
        out[HS + (size_t)b * HH + k]           = hnreg;  // h_255
        out[HS + BB * HH + (size_t)b * HH + k] = creg;   // c_255
    }
    float* hbout = out + HS + 2 * BB * HH + (size_t)b * HH * HH;
    HBQ_FOREACH(HBQ_OUT)
}

// ---------------------------------------------------------------------------
extern "C" void kernel_launch(void* const* d_in, const int* in_sizes, int n_in,
                              void* d_out, int out_size, void* d_ws,
                              size_t ws_size, hipStream_t stream) {
    const float* x     = (const float*)d_in[0];
    const float* Wx    = (const float*)d_in[1];
    const float* bx    = (const float*)d_in[2];
    const float* Wh    = (const float*)d_in[3];
    const float* bh    = (const float*)d_in[4];
    const float* w_mod = (const float*)d_in[5];
    const float* b_mod = (const float*)d_in[6];
    const float* w_fan = (const float*)d_in[7];
    const float* b_fan = (const float*)d_in[8];
    const float* alpha = (const float*)d_in[9];
    float* out = (float*)d_out;

    float* xf  = (float*)d_ws;                              // 32 MiB
    uint4* Wd3 = (uint4*)((char*)d_ws + 33554432);          // 512 KiB
    uint4* alQ = (uint4*)((char*)d_ws + 34078720);          // 128 KiB
    float* exD = (float*)((char*)d_ws + 34209792);          // 640 KiB
    int*   exF = (int*)((char*)d_ws + 34865152);            // 8 KiB

    hipLaunchKernelGGL(prep_wd3, dim3(128), dim3(256), 0, stream, Wh, Wd3);
    hipLaunchKernelGGL(prep_alq, dim3(32), dim3(256), 0, stream, alpha, alQ);
    hipLaunchKernelGGL(clear_flags, dim3(8), dim3(256), 0, stream, exF);
    hipLaunchKernelGGL(xf_gemm, dim3(16, 128), dim3(256), 0, stream,
                       x, Wx, bx, bh, xf);
    hipLaunchKernelGGL(scan_kernel, dim3(64), dim3(1024), 0, stream,
                       xf, Wd3, alQ, w_mod, b_mod, w_fan, b_fan,
                       exD, exF, out);
}

// Round 9
// 1015.385 us; speedup vs baseline: 3.9266x; 1.4371x over previous
//
#include <hip/hip_runtime.h>

// PlasticLSTM: T=256, B=32, I=128, H=256, 4H=1024, CLIP=2
// d_out: hs[T,B,H] ++ h[B,H] ++ c[B,H] ++ hebb[B,H,H]  (fp32, concat flat)
//
// Round-9: 4-way split-K. 128 blocks = 4 per batch; role r owns rows
// r*64..r*64+63 of the Wh dot, hebb, alpha. Weights (8 uint4) + alpha
// (2 uint4) are REGISTER-RESIDENT (fits now: ~58 live-through < 128 budget
// that rounds 5-7 established). Per-step exchange: each block publishes its
// 1024 gate partials (plast partials folded into the j-gate quarter) via
// agent-scope bypass atomics + monotone flag; cooperative combine (3 loads
// per thread) then redundant phase 2.

#define TT 256
#define BB 32
#define II 128
#define HH 256
#define G4 1024

typedef _Float16 h2_t __attribute__((ext_vector_type(2)));

__device__ __forceinline__ float sigm(float x) {
    return 1.0f / (1.0f + __expf(-x));
}
__device__ __forceinline__ float tanhfast(float x) {
    return 1.0f - 2.0f / (__expf(2.0f * x) + 1.0f);
}
__device__ __forceinline__ unsigned pkh(float lo, float hi) {
    h2_t v;
    v.x = (_Float16)lo;
    v.y = (_Float16)hi;
    return __builtin_bit_cast(unsigned, v);
}

#if __has_builtin(__builtin_amdgcn_fdot2)
__device__ __forceinline__ float dot2(unsigned a, unsigned b, float c) {
    return __builtin_amdgcn_fdot2(__builtin_bit_cast(h2_t, a),
                                  __builtin_bit_cast(h2_t, b), c, false);
}
#else
__device__ __forceinline__ float dot2(unsigned a, unsigned b, float c) {
    h2_t av = __builtin_bit_cast(h2_t, a), bv = __builtin_bit_cast(h2_t, b);
    return c + (float)av.x * (float)bv.x + (float)av.y * (float)bv.y;
}
#endif

__device__ __forceinline__ h2_t pkfma(h2_t a, h2_t b, h2_t c) {
#if __has_builtin(__builtin_elementwise_fma)
    return __builtin_elementwise_fma(a, b, c);
#else
    return a * b + c;
#endif
}
__device__ __forceinline__ h2_t clip2h(h2_t x) {
    const h2_t lo = {(_Float16)-2.0f, (_Float16)-2.0f};
    const h2_t hi = {(_Float16)2.0f, (_Float16)2.0f};
#if __has_builtin(__builtin_elementwise_max) && __has_builtin(__builtin_elementwise_min)
    return __builtin_elementwise_min(__builtin_elementwise_max(x, lo), hi);
#else
    h2_t r = x;
    r.x = r.x < lo.x ? lo.x : (r.x > hi.x ? hi.x : r.x);
    r.y = r.y < lo.y ? lo.y : (r.y > hi.y ? hi.y : r.y);
    return r;
#endif
}

// ---------------------------------------------------------------------------
// Wd3: idx = ro*4096 + g*4 + ri ; entry = 8 f16 of Wh[g][8*(4ro+ri) .. +7]
// ---------------------------------------------------------------------------
__global__ __launch_bounds__(256) void prep_wd3(const float* __restrict__ Wh,
                                                uint4* __restrict__ Wd3) {
    int idx = blockIdx.x * 256 + threadIdx.x;   // 32768
    int ro = idx >> 12, rem = idx & 4095;
    int g = rem >> 2, ri = rem & 3;
    int r8 = 4 * ro + ri;
    const float4* s = (const float4*)(Wh + (size_t)g * HH + (r8 << 3));
    float4 a = s[0], b2 = s[1];
    uint4 o;
    o.x = pkh(a.x, a.y);
    o.y = pkh(a.z, a.w);
    o.z = pkh(b2.x, b2.y);
    o.w = pkh(b2.z, b2.w);
    Wd3[idx] = o;
}

// ---------------------------------------------------------------------------
// alQ: idx = p4*256 + k -> uint4; comp j = f16 pair {alpha[2*(4p4+j)][k], +1}
// ---------------------------------------------------------------------------
__global__ __launch_bounds__(256) void prep_alq(const float* __restrict__ alpha,
                                                uint4* __restrict__ alQ) {
    int idx = blockIdx.x * 256 + threadIdx.x;   // 8192
    int p4 = idx >> 8, k = idx & 255;
    unsigned r[4];
#pragma unroll
    for (int j = 0; j < 4; ++j) {
        int p = 4 * p4 + j;
        float a0 = alpha[(size_t)(2 * p) * HH + k];
        float a1 = alpha[(size_t)(2 * p + 1) * HH + k];
        r[j] = pkh(a0, a1);
    }
    uint4 o; o.x = r[0]; o.y = r[1]; o.z = r[2]; o.w = r[3];
    alQ[idx] = o;
}

// flags must start <1 every launch
__global__ void clear_flags(int* __restrict__ f) {
    f[blockIdx.x * 256 + threadIdx.x] = 0;
}

// ---------------------------------------------------------------------------
// xf[t,b,g] = sum_i x[t,b,i]*Wx[g,i] + bx[g] + bh[g]
// ---------------------------------------------------------------------------
__global__ __launch_bounds__(256) void xf_gemm(const float* __restrict__ x,
                                               const float* __restrict__ Wx,
                                               const float* __restrict__ bx,
                                               const float* __restrict__ bh,
                                               float* __restrict__ xf) {
    __shared__ float As[64][37];
    __shared__ float Bs[64][37];
    const int tid = threadIdx.x;
    const int tx = tid & 15, ty = tid >> 4;
    const int m0 = blockIdx.y << 6;
    const int n0 = blockIdx.x << 6;
    float c[4][4] = {};

    for (int k0 = 0; k0 < II; k0 += 32) {
#pragma unroll
        for (int hh = 0; hh < 2; ++hh) {
            int row = (tid >> 3) + (hh << 5);
            int col = (tid & 7) << 2;
            float4 va = *(const float4*)(x + (size_t)(m0 + row) * II + k0 + col);
            As[row][col] = va.x; As[row][col + 1] = va.y;
            As[row][col + 2] = va.z; As[row][col + 3] = va.w;
            float4 vb = *(const float4*)(Wx + (size_t)(n0 + row) * II + k0 + col);
            Bs[row][col] = vb.x; Bs[row][col + 1] = vb.y;
            Bs[row][col + 2] = vb.z; Bs[row][col + 3] = vb.w;
        }
        __syncthreads();
#pragma unroll
        for (int kk = 0; kk < 32; ++kk) {
            float a[4], bb[4];
#pragma unroll
            for (int u = 0; u < 4; ++u) a[u] = As[(ty << 2) + u][kk];
#pragma unroll
            for (int v = 0; v < 4; ++v) bb[v] = Bs[(tx << 2) + v][kk];
#pragma unroll
            for (int u = 0; u < 4; ++u)
#pragma unroll
                for (int v = 0; v < 4; ++v)
                    c[u][v] = fmaf(a[u], bb[v], c[u][v]);
        }
        __syncthreads();
    }
    const int n = n0 + (tx << 2);
    float4 bxv = *(const float4*)(bx + n);
    float4 bhv = *(const float4*)(bh + n);
    float4 badd = {bxv.x + bhv.x, bxv.y + bhv.y, bxv.z + bhv.z, bxv.w + bhv.w};
#pragma unroll
    for (int u = 0; u < 4; ++u) {
        int m = m0 + (ty << 2) + u;
        float4 o = {c[u][0] + badd.x, c[u][1] + badd.y,
                    c[u][2] + badd.z, c[u][3] + badd.w};
        *(float4*)(xf + (size_t)m * G4 + n) = o;
    }
}

// ---------------------------------------------------------------------------
// hebb: 8 NAMED half2 regs/thread (rows r0g+2i, r0g+2i+1; r0g = r*64+rg*16).
// ---------------------------------------------------------------------------
#define HBQ_FOREACH(X) X(0) X(1) X(2) X(3) X(4) X(5) X(6) X(7)

#define HBQ_DECL(i) h2_t hp##i = {(_Float16)0.0f, (_Float16)0.0f};
#define HBQ_OUT(i) \
    hbout[(size_t)(r0g + 2 * i) * HH + k]     = (float)hp##i.x; \
    hbout[(size_t)(r0g + 2 * i + 1) * HH + k] = (float)hp##i.y;

#define HBQ_STEP(i, au, hou, hnu) { \
    h2_t al2 = __builtin_bit_cast(h2_t, au); \
    h2_t ho2 = __builtin_bit_cast(h2_t, hou); \
    h2_t hn2 = __builtin_bit_cast(h2_t, hnu); \
    hp##i = clip2h(pkfma(mj2, ho2, hp##i)); \
    h2_t hna = hn2 * al2; \
    pp = dot2(__builtin_bit_cast(unsigned, hna), \
              __builtin_bit_cast(unsigned, hp##i), pp); }

#define HBQ_CHUNK(q, AV, i0, i1, i2, i3) { \
    uint4 ho = hfO4[hb4 + (q)]; \
    uint4 hn = hfN4[hb4 + (q)]; \
    HBQ_STEP(i0, AV.x, ho.x, hn.x) \
    HBQ_STEP(i1, AV.y, ho.y, hn.y) \
    HBQ_STEP(i2, AV.z, ho.z, hn.z) \
    HBQ_STEP(i3, AV.w, ho.w, hn.w) }

#define HBV_STEP(i, hou) { \
    h2_t ho2 = __builtin_bit_cast(h2_t, hou); \
    hp##i = clip2h(pkfma(mj2, ho2, hp##i)); }
#define HBV_CHUNK(q, i0, i1, i2, i3) { \
    uint4 ho = hfO4[hb4 + (q)]; \
    HBV_STEP(i0, ho.x) HBV_STEP(i1, ho.y) \
    HBV_STEP(i2, ho.z) HBV_STEP(i3, ho.w) }

// 16 dot2 of one resident weight uint4 pair-group against 4 LDS h uint4
#define DOTW(W, HV) { \
    ac0 = dot2(W.x, HV.x, ac0); ac1 = dot2(W.y, HV.y, ac1); \
    ac2 = dot2(W.z, HV.z, ac2); ac3 = dot2(W.w, HV.w, ac3); }

__global__ __launch_bounds__(1024, 1) void scan_kernel(
    const float* __restrict__ xf,      // [T,B,4H], biases folded
    const uint4* __restrict__ Wd3,
    const uint4* __restrict__ alQ,
    const float* __restrict__ w_mod,
    const float* __restrict__ b_mod,
    const float* __restrict__ w_fan,
    const float* __restrict__ b_fan,
    float* __restrict__ exData,        // [32][4][2][1024] f32
    int* __restrict__ exFlag,          // [32][4] stride-64 ints
    float* __restrict__ out) {
    const int bid = blockIdx.x;
    const int r   = bid >> 5;          // role 0..3: rows r*64..r*64+63
    const int b   = bid & 31;          // batch element
    const int tid = threadIdx.x;
    const int k   = tid & (HH - 1);
    const int rg  = tid >> 8;          // 0..3
    const int r0g = r * 64 + rg * 16;  // first hebb row owned
    const int hb4 = r0g >> 3;          // uint4 index of row r0g in hf_s

    __shared__ alignas(16) unsigned short hf_s[2][HH];
    __shared__ float fioj_s[G4];
    __shared__ float pp_s[4][HH];
    __shared__ float red_s[4];

    HBQ_FOREACH(HBQ_DECL)

    if (tid < HH) {
        hf_s[0][tid] = 0;
        hf_s[1][tid] = 0;
    }
    if (tid < 4) red_s[tid] = 0.0f;
    __syncthreads();

    const float bmod = b_mod[0];
    const float wf = w_fan[k], bf = b_fan[k], wm = w_mod[k];
    float creg = 0.0f, jreg = 0.0f, hnreg = 0.0f;

    // ---- Register-resident weights (rows r*64..+63 for column g=tid) -----
    const uint4* wb = Wd3 + ((size_t)(2 * r) << 12) + (tid << 2);
    uint4 w0 = wb[0], w1 = wb[1], w2 = wb[2], w3 = wb[3];
    uint4 w4 = wb[4096], w5 = wb[4097], w6 = wb[4098], w7 = wb[4099];
    // ---- Register-resident alpha (8 row-pairs for column k) --------------
    uint4 aqA = alQ[(size_t)(8 * r + 2 * rg) * 256 + k];
    uint4 aqB = alQ[(size_t)(8 * r + 2 * rg + 1) * 256 + k];

    const float* xfp = xf + (size_t)b * G4 + tid;

    float* myEx  = exData + (size_t)((b * 4 + r) * 2) * 1024;
    const float* pEx1 = exData + (size_t)((b * 4 + ((r + 1) & 3)) * 2) * 1024;
    const float* pEx2 = exData + (size_t)((b * 4 + ((r + 2) & 3)) * 2) * 1024;
    const float* pEx3 = exData + (size_t)((b * 4 + ((r + 3) & 3)) * 2) * 1024;
    int* myFlag = exFlag + (b * 4 + r) * 64;
    const int* pfl = exFlag + (b * 4 + ((r + 1 + tid) & 3)) * 64; // lanes 0-2

    for (int t = 0; t < TT; ++t) {
        float xfv = 0.0f;
        if (rg == r) xfv = xfp[(size_t)t * BB * G4];   // wave-uniform branch

        // ---- Phase 1a: eta_{t-1}; deferred hebb update + plast(t) fused ---
        float eta = tanhfast(((red_s[0] + red_s[1]) + (red_s[2] + red_s[3])) + bmod);
        float mj = fmaf(eta, wf, bf) * jreg;    // 0 at t=0
        h2_t mj2;
        mj2.x = (_Float16)mj;
        mj2.y = mj2.x;
        const uint4* hfO4 = (const uint4*)hf_s[t & 1];        // h_{t-2}
        const uint4* hfN4 = (const uint4*)hf_s[(t & 1) ^ 1];  // h_{t-1}
        float pp = 0.0f;
        HBQ_CHUNK(0, aqA, 0, 1, 2, 3)
        HBQ_CHUNK(1, aqB, 4, 5, 6, 7)
        pp_s[rg][k] = pp;

        // ---- Phase 1b: quarter-K gate matvec, weights in registers --------
        float ac0 = 0.f, ac1 = 0.f, ac2 = 0.f, ac3 = 0.f;
        {
            const int hx = r << 3;
            uint4 h0 = hfN4[hx], h1 = hfN4[hx + 1];
            uint4 h2 = hfN4[hx + 2], h3 = hfN4[hx + 3];
            DOTW(w0, h0) DOTW(w1, h1) DOTW(w2, h2) DOTW(w3, h3)
            uint4 h4 = hfN4[hx + 4], h5 = hfN4[hx + 5];
            uint4 h6 = hfN4[hx + 6], h7 = hfN4[hx + 7];
            DOTW(w4, h4) DOTW(w5, h5) DOTW(w6, h6) DOTW(w7, h7)
        }
        float part = ((ac0 + ac1) + (ac2 + ac3)) + xfv;
        __syncthreads();                                   // B1 (pp_s ready)

        // fold own plast partial into the j-gate quarter (g = 768+k')
        if (tid >= 768) {
            int k2 = tid - 768;
            part += (pp_s[0][k2] + pp_s[1][k2]) + (pp_s[2][k2] + pp_s[3][k2]);
        }
        fioj_s[tid] = part;
        float* myExT = myEx + (t & 1) * 1024;
        __hip_atomic_store(&myExT[tid], part, __ATOMIC_RELAXED,
                           __HIP_MEMORY_SCOPE_AGENT);
        __syncthreads();                                   // B2 (drain stores)

        if (tid == 0)
            __hip_atomic_store(myFlag, t + 1, __ATOMIC_RELEASE,
                               __HIP_MEMORY_SCOPE_AGENT);
        if (tid < 3) {
            while (__hip_atomic_load(pfl, __ATOMIC_RELAXED,
                                     __HIP_MEMORY_SCOPE_AGENT) < t + 1) {}
        }
        __syncthreads();                                   // B3

        // ---- cooperative combine: 3 partner loads per thread --------------
        {
            const int off = (t & 1) * 1024 + tid;
            float tot = fioj_s[tid]
                + __hip_atomic_load(&pEx1[off], __ATOMIC_RELAXED,
                                    __HIP_MEMORY_SCOPE_AGENT)
                + __hip_atomic_load(&pEx2[off], __ATOMIC_RELAXED,
                                    __HIP_MEMORY_SCOPE_AGENT)
                + __hip_atomic_load(&pEx3[off], __ATOMIC_RELAXED,
                                    __HIP_MEMORY_SCOPE_AGENT);
            fioj_s[tid] = tot;
        }
        __syncthreads();                                   // B3b

        // ---- Phase 2: cell update (redundant across roles & rg) -----------
        float fg = sigm(fioj_s[k]);
        float ig = sigm(fioj_s[HH + k]);
        float og = sigm(fioj_s[2 * HH + k]);
        float jp = fioj_s[3 * HH + k];     // plast already folded in
        jreg = tanhfast(jp);
        creg = fmaf(fg, creg, ig * jreg);
        hnreg = og * tanhfast(creg);
        if (rg == 0) {   // waves 0-3, wave-uniform
            _Float16 hh = (_Float16)hnreg;
            hf_s[t & 1][k] = __builtin_bit_cast(unsigned short, hh);
            if (r == 0) out[((size_t)t * BB + b) * HH + k] = hnreg;
            float e = creg * wm;
#pragma unroll
            for (int m = 32; m >= 1; m >>= 1) e += __shfl_xor(e, m, 64);
            if ((k & 63) == 0) red_s[k >> 6] = e;
        }
        __syncthreads();                                   // B4
    }

    // ---- Final deferred hebb update (step 255's delta) -------------------
    {
        float eta = tanhfast(((red_s[0] + red_s[1]) + (red_s[2] + red_s[3])) + bmod);
        float mj = fmaf(eta, wf, bf) * jreg;
        h2_t mj2;
        mj2.x = (_Float16)mj;
        mj2.y = mj2.x;
        const uint4* hfO4 = (const uint4*)hf_s[0];   // h_254 (TT even)
        HBV_CHUNK(0, 0, 1, 2, 3)
        HBV_CHUNK(1, 4, 5, 6, 7)
    }

    const size_t HS = (size_t)TT * BB * HH;
    if (r == 0 && rg == 0) {
        out[HS + (size_t)b * HH + k]           = hnreg;  // h_255
        out[HS + BB * HH + (size_t)b * HH + k] = creg;   // c_255
    }
    float* hbout = out + HS + 2 * BB * HH + (size_t)b * HH * HH;
    HBQ_FOREACH(HBQ_OUT)
}

// ---------------------------------------------------------------------------
extern "C" void kernel_launch(void* const* d_in, const int* in_sizes, int n_in,
                              void* d_out, int out_size, void* d_ws,
                              size_t ws_size, hipStream_t stream) {
    const float* x     = (const float*)d_in[0];
    const float* Wx    = (const float*)d_in[1];
    const float* bx    = (const float*)d_in[2];
    const float* Wh    = (const float*)d_in[3];
    const float* bh    = (const float*)d_in[4];
    const float* w_mod = (const float*)d_in[5];
    const float* b_mod = (const float*)d_in[6];
    const float* w_fan = (const float*)d_in[7];
    const float* b_fan = (const float*)d_in[8];
    const float* alpha = (const float*)d_in[9];
    float* out = (float*)d_out;

    float* xf  = (float*)d_ws;                              // 32 MiB
    uint4* Wd3 = (uint4*)((char*)d_ws + 33554432);          // 512 KiB
    uint4* alQ = (uint4*)((char*)d_ws + 34078720);          // 128 KiB
    float* exD = (float*)((char*)d_ws + 34209792);          // 1 MiB
    int*   exF = (int*)((char*)d_ws + 35258368);            // 32 KiB

    hipLaunchKernelGGL(prep_wd3, dim3(128), dim3(256), 0, stream, Wh, Wd3);
    hipLaunchKernelGGL(prep_alq, dim3(32), dim3(256), 0, stream, alpha, alQ);
    hipLaunchKernelGGL(clear_flags, dim3(32), dim3(256), 0, stream, exF);
    hipLaunchKernelGGL(xf_gemm, dim3(16, 128), dim3(256), 0, stream,
                       x, Wx, bx, bh, xf);
    hipLaunchKernelGGL(scan_kernel, dim3(128), dim3(1024), 0, stream,
                       xf, Wd3, alQ, w_mod, b_mod, w_fan, b_fan,
                       exD, exF, out);
}

// Round 10
// 906.707 us; speedup vs baseline: 4.3972x; 1.1199x over previous
//
#include <hip/hip_runtime.h>

// PlasticLSTM: T=256, B=32, I=128, H=256, 4H=1024, CLIP=2
// d_out: hs[T,B,H] ++ h[B,H] ++ c[B,H] ++ hebb[B,H,H]  (fp32, concat flat)
//
// Round-10: 4-way split-K (128 blocks, as round 9) with a SELF-SIGNALING
// tagged exchange: each published element is a single 8-byte atomic
// {tag=t+1 | f32 value}; partners poll the tag directly. Removes the flag
// round trip and 2 of 5 per-step barriers. Ping-pong slots preserve the
// 2-step clobber-safety proof; exact tag match makes stale/poison harmless
// (no clear kernel needed).

#define TT 256
#define BB 32
#define II 128
#define HH 256
#define G4 1024

typedef _Float16 h2_t __attribute__((ext_vector_type(2)));
typedef unsigned long long u64;

__device__ __forceinline__ float sigm(float x) {
    return 1.0f / (1.0f + __expf(-x));
}
__device__ __forceinline__ float tanhfast(float x) {
    return 1.0f - 2.0f / (__expf(2.0f * x) + 1.0f);
}
__device__ __forceinline__ unsigned pkh(float lo, float hi) {
    h2_t v;
    v.x = (_Float16)lo;
    v.y = (_Float16)hi;
    return __builtin_bit_cast(unsigned, v);
}

#if __has_builtin(__builtin_amdgcn_fdot2)
__device__ __forceinline__ float dot2(unsigned a, unsigned b, float c) {
    return __builtin_amdgcn_fdot2(__builtin_bit_cast(h2_t, a),
                                  __builtin_bit_cast(h2_t, b), c, false);
}
#else
__device__ __forceinline__ float dot2(unsigned a, unsigned b, float c) {
    h2_t av = __builtin_bit_cast(h2_t, a), bv = __builtin_bit_cast(h2_t, b);
    return c + (float)av.x * (float)bv.x + (float)av.y * (float)bv.y;
}
#endif

__device__ __forceinline__ h2_t pkfma(h2_t a, h2_t b, h2_t c) {
#if __has_builtin(__builtin_elementwise_fma)
    return __builtin_elementwise_fma(a, b, c);
#else
    return a * b + c;
#endif
}
__device__ __forceinline__ h2_t clip2h(h2_t x) {
    const h2_t lo = {(_Float16)-2.0f, (_Float16)-2.0f};
    const h2_t hi = {(_Float16)2.0f, (_Float16)2.0f};
#if __has_builtin(__builtin_elementwise_max) && __has_builtin(__builtin_elementwise_min)
    return __builtin_elementwise_min(__builtin_elementwise_max(x, lo), hi);
#else
    h2_t r = x;
    r.x = r.x < lo.x ? lo.x : (r.x > hi.x ? hi.x : r.x);
    r.y = r.y < lo.y ? lo.y : (r.y > hi.y ? hi.y : r.y);
    return r;
#endif
}

// ---------------------------------------------------------------------------
// Wd3: idx = ro*4096 + g*4 + ri ; entry = 8 f16 of Wh[g][8*(4ro+ri) .. +7]
// ---------------------------------------------------------------------------
__global__ __launch_bounds__(256) void prep_wd3(const float* __restrict__ Wh,
                                                uint4* __restrict__ Wd3) {
    int idx = blockIdx.x * 256 + threadIdx.x;   // 32768
    int ro = idx >> 12, rem = idx & 4095;
    int g = rem >> 2, ri = rem & 3;
    int r8 = 4 * ro + ri;
    const float4* s = (const float4*)(Wh + (size_t)g * HH + (r8 << 3));
    float4 a = s[0], b2 = s[1];
    uint4 o;
    o.x = pkh(a.x, a.y);
    o.y = pkh(a.z, a.w);
    o.z = pkh(b2.x, b2.y);
    o.w = pkh(b2.z, b2.w);
    Wd3[idx] = o;
}

// ---------------------------------------------------------------------------
// alQ: idx = p4*256 + k -> uint4; comp j = f16 pair {alpha[2*(4p4+j)][k], +1}
// ---------------------------------------------------------------------------
__global__ __launch_bounds__(256) void prep_alq(const float* __restrict__ alpha,
                                                uint4* __restrict__ alQ) {
    int idx = blockIdx.x * 256 + threadIdx.x;   // 8192
    int p4 = idx >> 8, k = idx & 255;
    unsigned r[4];
#pragma unroll
    for (int j = 0; j < 4; ++j) {
        int p = 4 * p4 + j;
        float a0 = alpha[(size_t)(2 * p) * HH + k];
        float a1 = alpha[(size_t)(2 * p + 1) * HH + k];
        r[j] = pkh(a0, a1);
    }
    uint4 o; o.x = r[0]; o.y = r[1]; o.z = r[2]; o.w = r[3];
    alQ[idx] = o;
}

// ---------------------------------------------------------------------------
// xf[t,b,g] = sum_i x[t,b,i]*Wx[g,i] + bx[g] + bh[g]
// ---------------------------------------------------------------------------
__global__ __launch_bounds__(256) void xf_gemm(const float* __restrict__ x,
                                               const float* __restrict__ Wx,
                                               const float* __restrict__ bx,
                                               const float* __restrict__ bh,
                                               float* __restrict__ xf) {
    __shared__ float As[64][37];
    __shared__ float Bs[64][37];
    const int tid = threadIdx.x;
    const int tx = tid & 15, ty = tid >> 4;
    const int m0 = blockIdx.y << 6;
    const int n0 = blockIdx.x << 6;
    float c[4][4] = {};

    for (int k0 = 0; k0 < II; k0 += 32) {
#pragma unroll
        for (int hh = 0; hh < 2; ++hh) {
            int row = (tid >> 3) + (hh << 5);
            int col = (tid & 7) << 2;
            float4 va = *(const float4*)(x + (size_t)(m0 + row) * II + k0 + col);
            As[row][col] = va.x; As[row][col + 1] = va.y;
            As[row][col + 2] = va.z; As[row][col + 3] = va.w;
            float4 vb = *(const float4*)(Wx + (size_t)(n0 + row) * II + k0 + col);
            Bs[row][col] = vb.x; Bs[row][col + 1] = vb.y;
            Bs[row][col + 2] = vb.z; Bs[row][col + 3] = vb.w;
        }
        __syncthreads();
#pragma unroll
        for (int kk = 0; kk < 32; ++kk) {
            float a[4], bb[4];
#pragma unroll
            for (int u = 0; u < 4; ++u) a[u] = As[(ty << 2) + u][kk];
#pragma unroll
            for (int v = 0; v < 4; ++v) bb[v] = Bs[(tx << 2) + v][kk];
#pragma unroll
            for (int u = 0; u < 4; ++u)
#pragma unroll
                for (int v = 0; v < 4; ++v)
                    c[u][v] = fmaf(a[u], bb[v], c[u][v]);
        }
        __syncthreads();
    }
    const int n = n0 + (tx << 2);
    float4 bxv = *(const float4*)(bx + n);
    float4 bhv = *(const float4*)(bh + n);
    float4 badd = {bxv.x + bhv.x, bxv.y + bhv.y, bxv.z + bhv.z, bxv.w + bhv.w};
#pragma unroll
    for (int u = 0; u < 4; ++u) {
        int m = m0 + (ty << 2) + u;
        float4 o = {c[u][0] + badd.x, c[u][1] + badd.y,
                    c[u][2] + badd.z, c[u][3] + badd.w};
        *(float4*)(xf + (size_t)m * G4 + n) = o;
    }
}

// ---------------------------------------------------------------------------
// hebb: 8 NAMED half2 regs/thread (rows r0g+2i, r0g+2i+1; r0g = r*64+rg*16).
// ---------------------------------------------------------------------------
#define HBQ_FOREACH(X) X(0) X(1) X(2) X(3) X(4) X(5) X(6) X(7)

#define HBQ_DECL(i) h2_t hp##i = {(_Float16)0.0f, (_Float16)0.0f};
#define HBQ_OUT(i) \
    hbout[(size_t)(r0g + 2 * i) * HH + k]     = (float)hp##i.x; \
    hbout[(size_t)(r0g + 2 * i + 1) * HH + k] = (float)hp##i.y;

#define HBQ_STEP(i, au, hou, hnu) { \
    h2_t al2 = __builtin_bit_cast(h2_t, au); \
    h2_t ho2 = __builtin_bit_cast(h2_t, hou); \
    h2_t hn2 = __builtin_bit_cast(h2_t, hnu); \
    hp##i = clip2h(pkfma(mj2, ho2, hp##i)); \
    h2_t hna = hn2 * al2; \
    pp = dot2(__builtin_bit_cast(unsigned, hna), \
              __builtin_bit_cast(unsigned, hp##i), pp); }

#define HBQ_CHUNK(q, AV, i0, i1, i2, i3) { \
    uint4 ho = hfO4[hb4 + (q)]; \
    uint4 hn = hfN4[hb4 + (q)]; \
    HBQ_STEP(i0, AV.x, ho.x, hn.x) \
    HBQ_STEP(i1, AV.y, ho.y, hn.y) \
    HBQ_STEP(i2, AV.z, ho.z, hn.z) \
    HBQ_STEP(i3, AV.w, ho.w, hn.w) }

#define HBV_STEP(i, hou) { \
    h2_t ho2 = __builtin_bit_cast(h2_t, hou); \
    hp##i = clip2h(pkfma(mj2, ho2, hp##i)); }
#define HBV_CHUNK(q, i0, i1, i2, i3) { \
    uint4 ho = hfO4[hb4 + (q)]; \
    HBV_STEP(i0, ho.x) HBV_STEP(i1, ho.y) \
    HBV_STEP(i2, ho.z) HBV_STEP(i3, ho.w) }

#define DOTW(W, HV) { \
    ac0 = dot2(W.x, HV.x, ac0); ac1 = dot2(W.y, HV.y, ac1); \
    ac2 = dot2(W.z, HV.z, ac2); ac3 = dot2(W.w, HV.w, ac3); }

__global__ __launch_bounds__(1024, 1) void scan_kernel(
    const float* __restrict__ xf,      // [T,B,4H], biases folded
    const uint4* __restrict__ Wd3,
    const uint4* __restrict__ alQ,
    const float* __restrict__ w_mod,
    const float* __restrict__ b_mod,
    const float* __restrict__ w_fan,
    const float* __restrict__ b_fan,
    u64* __restrict__ exData,          // [32][4][2][1024] u64 {tag|f32}
    float* __restrict__ out) {
    const int bid = blockIdx.x;
    const int r   = bid >> 5;          // role 0..3: rows r*64..r*64+63
    const int b   = bid & 31;          // batch element
    const int tid = threadIdx.x;
    const int k   = tid & (HH - 1);
    const int rg  = tid >> 8;          // 0..3
    const int r0g = r * 64 + rg * 16;  // first hebb row owned
    const int hb4 = r0g >> 3;          // uint4 index of row r0g in hf_s

    __shared__ alignas(16) unsigned short hf_s[2][HH];
    __shared__ float fioj_s[G4];
    __shared__ float pp_s[4][HH];
    __shared__ float red_s[4];

    HBQ_FOREACH(HBQ_DECL)

    if (tid < HH) {
        hf_s[0][tid] = 0;
        hf_s[1][tid] = 0;
    }
    if (tid < 4) red_s[tid] = 0.0f;
    __syncthreads();

    const float bmod = b_mod[0];
    const float wf = w_fan[k], bf = b_fan[k], wm = w_mod[k];
    float creg = 0.0f, jreg = 0.0f, hnreg = 0.0f;

    // ---- Register-resident weights (rows r*64..+63 for column g=tid) -----
    const uint4* wb = Wd3 + ((size_t)(2 * r) << 12) + (tid << 2);
    uint4 w0 = wb[0], w1 = wb[1], w2 = wb[2], w3 = wb[3];
    uint4 w4 = wb[4096], w5 = wb[4097], w6 = wb[4098], w7 = wb[4099];
    // ---- Register-resident alpha (8 row-pairs for column k) --------------
    uint4 aqA = alQ[(size_t)(8 * r + 2 * rg) * 256 + k];
    uint4 aqB = alQ[(size_t)(8 * r + 2 * rg + 1) * 256 + k];

    const float* xfp = xf + (size_t)b * G4 + tid;

    u64* myEx = exData + (size_t)((b * 4 + r) * 2) * 1024;
    const u64* pEx1 = exData + (size_t)((b * 4 + ((r + 1) & 3)) * 2) * 1024;
    const u64* pEx2 = exData + (size_t)((b * 4 + ((r + 2) & 3)) * 2) * 1024;
    const u64* pEx3 = exData + (size_t)((b * 4 + ((r + 3) & 3)) * 2) * 1024;

    for (int t = 0; t < TT; ++t) {
        float xfv = 0.0f;
        if (rg == r) xfv = xfp[(size_t)t * BB * G4];   // wave-uniform branch

        // ---- Phase 1a: eta_{t-1}; deferred hebb update + plast(t) fused ---
        float eta = tanhfast(((red_s[0] + red_s[1]) + (red_s[2] + red_s[3])) + bmod);
        float mj = fmaf(eta, wf, bf) * jreg;    // 0 at t=0
        h2_t mj2;
        mj2.x = (_Float16)mj;
        mj2.y = mj2.x;
        const uint4* hfO4 = (const uint4*)hf_s[t & 1];        // h_{t-2}
        const uint4* hfN4 = (const uint4*)hf_s[(t & 1) ^ 1];  // h_{t-1}
        float pp = 0.0f;
        HBQ_CHUNK(0, aqA, 0, 1, 2, 3)
        HBQ_CHUNK(1, aqB, 4, 5, 6, 7)
        pp_s[rg][k] = pp;

        // ---- Phase 1b: quarter-K gate matvec, weights in registers --------
        float ac0 = 0.f, ac1 = 0.f, ac2 = 0.f, ac3 = 0.f;
        {
            const int hx = r << 3;
            uint4 h0 = hfN4[hx], h1 = hfN4[hx + 1];
            uint4 h2 = hfN4[hx + 2], h3 = hfN4[hx + 3];
            DOTW(w0, h0) DOTW(w1, h1) DOTW(w2, h2) DOTW(w3, h3)
            uint4 h4 = hfN4[hx + 4], h5 = hfN4[hx + 5];
            uint4 h6 = hfN4[hx + 6], h7 = hfN4[hx + 7];
            DOTW(w4, h4) DOTW(w5, h5) DOTW(w6, h6) DOTW(w7, h7)
        }
        float part = ((ac0 + ac1) + (ac2 + ac3)) + xfv;
        __syncthreads();                                   // B1 (pp_s ready)

        // fold own plast partial into the j-gate quarter (g = 768+k')
        if (tid >= 768) {
            int k2 = tid - 768;
            part += (pp_s[0][k2] + pp_s[1][k2]) + (pp_s[2][k2] + pp_s[3][k2]);
        }

        // ---- publish tagged {t+1 | part}: the store IS the signal ---------
        const unsigned tag = (unsigned)(t + 1);
        const int off = (t & 1) * 1024 + tid;
        {
            u64 pkv = ((u64)tag << 32) |
                      (u64)__builtin_bit_cast(unsigned, part);
            __hip_atomic_store(&myEx[off], pkv, __ATOMIC_RELAXED,
                               __HIP_MEMORY_SCOPE_AGENT);
        }

        // ---- poll the 3 partner values (interleaved, latencies overlap) ---
        {
            float s1 = 0.f, s2 = 0.f, s3 = 0.f;
            bool d1 = false, d2 = false, d3 = false;
            do {
                if (!d1) {
                    u64 v = __hip_atomic_load(&pEx1[off], __ATOMIC_RELAXED,
                                              __HIP_MEMORY_SCOPE_AGENT);
                    if ((unsigned)(v >> 32) == tag) {
                        s1 = __builtin_bit_cast(float, (unsigned)v);
                        d1 = true;
                    }
                }
                if (!d2) {
                    u64 v = __hip_atomic_load(&pEx2[off], __ATOMIC_RELAXED,
                                              __HIP_MEMORY_SCOPE_AGENT);
                    if ((unsigned)(v >> 32) == tag) {
                        s2 = __builtin_bit_cast(float, (unsigned)v);
                        d2 = true;
                    }
                }
                if (!d3) {
                    u64 v = __hip_atomic_load(&pEx3[off], __ATOMIC_RELAXED,
                                              __HIP_MEMORY_SCOPE_AGENT);
                    if ((unsigned)(v >> 32) == tag) {
                        s3 = __builtin_bit_cast(float, (unsigned)v);
                        d3 = true;
                    }
                }
            } while (!(d1 && d2 && d3));
            fioj_s[tid] = part + ((s1 + s2) + s3);
        }
        __syncthreads();                                   // B2 (fioj ready)

        // ---- Phase 2: cell update (redundant across roles & rg) -----------
        float fg = sigm(fioj_s[k]);
        float ig = sigm(fioj_s[HH + k]);
        float og = sigm(fioj_s[2 * HH + k]);
        float jp = fioj_s[3 * HH + k];     // plast already folded in
        jreg = tanhfast(jp);
        creg = fmaf(fg, creg, ig * jreg);
        hnreg = og * tanhfast(creg);
        if (rg == 0) {   // waves 0-3, wave-uniform
            _Float16 hh = (_Float16)hnreg;
            hf_s[t & 1][k] = __builtin_bit_cast(unsigned short, hh);
            if (r == 0) out[((size_t)t * BB + b) * HH + k] = hnreg;
            float e = creg * wm;
#pragma unroll
            for (int m = 32; m >= 1; m >>= 1) e += __shfl_xor(e, m, 64);
            if ((k & 63) == 0) red_s[k >> 6] = e;
        }
        __syncthreads();                                   // B3 (hf_s ready)
    }

    // ---- Final deferred hebb update (step 255's delta) -------------------
    {
        float eta = tanhfast(((red_s[0] + red_s[1]) + (red_s[2] + red_s[3])) + bmod);
        float mj = fmaf(eta, wf, bf) * jreg;
        h2_t mj2;
        mj2.x = (_Float16)mj;
        mj2.y = mj2.x;
        const uint4* hfO4 = (const uint4*)hf_s[0];   // h_254 (TT even)
        HBV_CHUNK(0, 0, 1, 2, 3)
        HBV_CHUNK(1, 4, 5, 6, 7)
    }

    const size_t HS = (size_t)TT * BB * HH;
    if (r == 0 && rg == 0) {
        out[HS + (size_t)b * HH + k]           = hnreg;  // h_255
        out[HS + BB * HH + (size_t)b * HH + k] = creg;   // c_255
    }
    float* hbout = out + HS + 2 * BB * HH + (size_t)b * HH * HH;
    HBQ_FOREACH(HBQ_OUT)
}

// ---------------------------------------------------------------------------
extern "C" void kernel_launch(void* const* d_in, const int* in_sizes, int n_in,
                              void* d_out, int out_size, void* d_ws,
                              size_t ws_size, hipStream_t stream) {
    const float* x     = (const float*)d_in[0];
    const float* Wx    = (const float*)d_in[1];
    const float* bx    = (const float*)d_in[2];
    const float* Wh    = (const float*)d_in[3];
    const float* bh    = (const float*)d_in[4];
    const float* w_mod = (const float*)d_in[5];
    const float* b_mod = (const float*)d_in[6];
    const float* w_fan = (const float*)d_in[7];
    const float* b_fan = (const float*)d_in[8];
    const float* alpha = (const float*)d_in[9];
    float* out = (float*)d_out;

    float* xf  = (float*)d_ws;                              // 32 MiB
    uint4* Wd3 = (uint4*)((char*)d_ws + 33554432);          // 512 KiB
    uint4* alQ = (uint4*)((char*)d_ws + 34078720);          // 128 KiB
    u64*   exD = (u64*)((char*)d_ws + 34209792);            // 2 MiB

    hipLaunchKernelGGL(prep_wd3, dim3(128), dim3(256), 0, stream, Wh, Wd3);
    hipLaunchKernelGGL(prep_alq, dim3(32), dim3(256), 0, stream, alpha, alQ);
    hipLaunchKernelGGL(xf_gemm, dim3(16, 128), dim3(256), 0, stream,
                       x, Wx, bx, bh, xf);
    hipLaunchKernelGGL(scan_kernel, dim3(128), dim3(1024), 0, stream,
                       xf, Wd3, alQ, w_mod, b_mod, w_fan, b_fan,
                       exD, out);
}